// Round 9
// baseline (73.283 us; speedup 1.0000x reference)
//
#include <hip/hip_runtime.h>
#include <stdint.h>

typedef _Float16 f16;
typedef _Float16 f16x8 __attribute__((ext_vector_type(8)));
typedef _Float16 f16x4 __attribute__((ext_vector_type(4)));
typedef float f32x4 __attribute__((ext_vector_type(4)));

#define D_DIM 4096
#define H_DIM 256
#define E_DIM 64

// ---- merged pack: w1 [4096][256] -> w1s fragment order; w2 [256][64] -> w2s ----
// w1s f16 index: ((kt*16 + c16)*2 + kk)*512 + lane*8 + j
//   = w1[(kt*64 + kk*32 + (lane>>4)*8 + j)][c16*16 + (lane&15)]
__global__ void pack_kernel(const float* __restrict__ w1, f16* __restrict__ w1s,
                            const float* __restrict__ w2, f16* __restrict__ w2s) {
  const int b = blockIdx.x;
  const int t = threadIdx.x;
  if (b < 512) {
    const int u = b * 256 + t;
    const int lane = u & 63;
    const int kk = (u >> 6) & 1;
    const int c16 = (u >> 7) & 15;
    const int kt = u >> 11;
    const int g = lane >> 4, r = lane & 15;
    const int k0 = kt * 64 + kk * 32 + g * 8;
    const int col = c16 * 16 + r;
    f16x8 o;
#pragma unroll
    for (int j = 0; j < 8; ++j) o[j] = (f16)w1[(size_t)(k0 + j) * H_DIM + col];
    *(f16x8*)(w1s + (size_t)u * 8) = o;
  } else {
    const int u = (b - 512) * 256 + t;
    const int lane = u & 63;
    const int ks = (u >> 6) & 7;
    const int cg = u >> 9;
    const int g = lane >> 4, r = lane & 15;
    const int k0 = ks * 32 + g * 8;
    const int col = cg * 16 + r;
    f16x8 o;
#pragma unroll
    for (int j = 0; j < 8; ++j) o[j] = (f16)w2[(size_t)(k0 + j) * E_DIM + col];
    *(f16x8*)(w2s + (size_t)u * 8) = o;
  }
}

// ---- fused: h=relu(x@w1+b1); u=h@w2+b2; p=sparsemax(u). Full-K per block. ----
// grid 256, 512 thr (8 waves: wm 0..1 x wc 0..3). 8 K-steps of BK=512 f32.
// Staging: each wave streams 4 rows, 8x 1KB-contiguous bursts (DRAM page-friendly).
__launch_bounds__(512, 2)
__global__ void fused_kernel(const float* __restrict__ x,
                             const f16* __restrict__ w1s,
                             const float* __restrict__ b1,
                             const f16* __restrict__ w2s,
                             const float* __restrict__ b2,
                             float* __restrict__ out) {
  __shared__ __align__(16) char smem[65536];   // 2 x 32KB x-tile (f16 [32][512] swizzled)

  const int t = threadIdx.x;
  const int lane = t & 63;
  const int wn = t >> 6;          // 0..7
  const int wm = wn >> 2;         // 0..1 (16-row half)
  const int wc = wn & 3;          // 0..3 (64-col group)
  const int g = lane >> 4, r = lane & 15;
  const int brow = blockIdx.x * 32;

  // staging: wave wn owns rows wn*4 .. wn*4+3
  const float* xt = x + (size_t)(brow + wn * 4) * D_DIM + lane * 4;
  const f16* bptr = w1s + (size_t)(wc * 8) * 512 + lane * 8;

  f32x4 acc[4] = {{0.f,0.f,0.f,0.f},{0.f,0.f,0.f,0.f},{0.f,0.f,0.f,0.f},{0.f,0.f,0.f,0.f}};
  f16x8 Ba[8], Bb[8];
  float4 xr[8];

#define LDXS(s)                                                          \
  {                                                                      \
    _Pragma("unroll") for (int i = 0; i < 8; ++i)                        \
      xr[i] = *(const float4*)(xt + (size_t)(i >> 1) * D_DIM +           \
                               (s) * 512 + (i & 1) * 256);               \
  }
#define STW(dst)                                                         \
  {                                                                      \
    _Pragma("unroll") for (int i = 0; i < 8; ++i) {                      \
      const int row_ = wn * 4 + (i >> 1);                                \
      const int col_ = (i & 1) * 256 + lane * 4;                         \
      f16x4 hv_;                                                         \
      hv_[0] = (f16)xr[i].x; hv_[1] = (f16)xr[i].y;                      \
      hv_[2] = (f16)xr[i].z; hv_[3] = (f16)xr[i].w;                      \
      *(f16x4*)((dst) + row_ * 512 + (col_ ^ ((row_ & 7) << 3))) = hv_;  \
    }                                                                    \
  }
#define LDB(kt, B)                                                       \
  {                                                                      \
    const f16* p_ = bptr + (size_t)(kt) * 16384;                         \
    _Pragma("unroll") for (int q = 0; q < 8; ++q)                        \
      (B)[q] = *(const f16x8*)(p_ + q * 512);                            \
  }
#define COMP_KT(bufp, j, B)                                              \
  {                                                                      \
    _Pragma("unroll") for (int kk = 0; kk < 2; ++kk) {                   \
      const int row_ = wm * 16 + r;                                      \
      const int kb_ = (j) * 64 + kk * 32 + g * 8;                        \
      const f16x8 af_ =                                                  \
          *(const f16x8*)((bufp) + row_ * 512 + (kb_ ^ ((row_ & 7) << 3))); \
      _Pragma("unroll") for (int nf = 0; nf < 4; ++nf)                   \
        acc[nf] = __builtin_amdgcn_mfma_f32_16x16x32_f16(                \
            af_, (B)[nf * 2 + kk], acc[nf], 0, 0, 0);                    \
    }                                                                    \
  }
#define BAR()                                          \
  asm volatile("s_waitcnt lgkmcnt(0)" ::: "memory");   \
  __builtin_amdgcn_s_barrier();
#define MIN63(v) ((v) > 63 ? 63 : (v))

  // prologue: xr = x(step0); B(kt 0,1); buf0 = cvt(xr)
  LDXS(0);
  LDB(0, Ba);
  LDB(1, Bb);
  STW((f16*)smem);
  BAR();

#pragma unroll 1
  for (int s = 0; s < 8; ++s) {
    f16* bc = (f16*)(smem + ((s & 1) << 15));
    if (s < 7) LDXS(s + 1);                 // issue next-step x early (page-sequential)
    const int kt0 = s * 8;
    // 8 sub-K steps, B dist-2 reg prefetch (alternating slots, all static)
    COMP_KT(bc, 0, Ba); LDB(MIN63(kt0 + 2), Ba);
    COMP_KT(bc, 1, Bb); LDB(MIN63(kt0 + 3), Bb);
    COMP_KT(bc, 2, Ba); LDB(MIN63(kt0 + 4), Ba);
    COMP_KT(bc, 3, Bb); LDB(MIN63(kt0 + 5), Bb);
    COMP_KT(bc, 4, Ba); LDB(MIN63(kt0 + 6), Ba);
    COMP_KT(bc, 5, Bb); LDB(MIN63(kt0 + 7), Bb);
    COMP_KT(bc, 6, Ba); LDB(MIN63(kt0 + 8), Ba);
    COMP_KT(bc, 7, Bb); LDB(MIN63(kt0 + 9), Bb);
    BAR();
    if (s < 7) {
      f16* bn = (f16*)(smem + (((s + 1) & 1) << 15));
      STW(bn);
      BAR();
    }
  }

  // ---- epilogue 1: h = relu(acc + b1) -> h_lds [32][256] f16 swizzled ----
  f16* h_lds = (f16*)smem;                 // overlays buf0 (free: last COMP used buf1)
  float* u_lds = (float*)(smem + 16384);
#pragma unroll
  for (int nf = 0; nf < 4; ++nf) {
    const int col = wc * 64 + nf * 16 + r;
    const float bias = b1[col];
#pragma unroll
    for (int jj = 0; jj < 4; ++jj) {
      const int row = wm * 16 + g * 4 + jj;
      const float v = fmaxf(acc[nf][jj] + bias, 0.f);
      h_lds[row * 256 + (col ^ ((row & 7) << 3))] = (f16)v;
    }
  }
  __syncthreads();

  // ---- epilogue 2: u = h @ w2 + b2 (one 16x16 tile per wave) ----
  const int rh2 = wn & 1;
  const int cg = wn >> 1;
  f32x4 acc2 = {0.f, 0.f, 0.f, 0.f};
  const f16* w2p = w2s + (size_t)(cg * 8) * 512 + lane * 8;
#pragma unroll
  for (int ksi = 0; ksi < 8; ++ksi) {
    const int arow = rh2 * 16 + r;
    const int kb = ksi * 32 + g * 8;
    const f16x8 af = *(const f16x8*)(h_lds + arow * 256 + (kb ^ ((arow & 7) << 3)));
    const f16x8 bf = *(const f16x8*)(w2p + ksi * 512);
    acc2 = __builtin_amdgcn_mfma_f32_16x16x32_f16(af, bf, acc2, 0, 0, 0);
  }
  {
    const int col = cg * 16 + r;
    const float bias = b2[col];
#pragma unroll
    for (int j = 0; j < 4; ++j) {
      const int rr = rh2 * 16 + g * 4 + j;
      u_lds[rr * 64 + col] = acc2[j] + bias;
    }
  }
  __syncthreads();

  // ---- epilogue 3: bisection sparsemax; 16 lanes/row, 4 vals/lane ----
  const int srow = wn * 4 + (lane >> 4);
  const int scol = (lane & 15) << 2;
  const float4 uv = *(const float4*)(u_lds + srow * 64 + scol);
  float u0 = uv.x, u1 = uv.y, u2 = uv.z, u3 = uv.w;

  float mx = fmaxf(fmaxf(u0, u1), fmaxf(u2, u3));
  float mn = fminf(fminf(u0, u1), fminf(u2, u3));
#pragma unroll
  for (int m = 1; m < 16; m <<= 1) {
    mx = fmaxf(mx, __shfl_xor(mx, m));
    mn = fminf(mn, __shfl_xor(mn, m));
  }
  float lo = mn - 10.0f, hi = mx;
#pragma unroll 1
  for (int it = 0; it < 32; ++it) {
    const float mid = 0.5f * (lo + hi);
    float sm = fmaxf(u0 - mid, 0.f) + fmaxf(u1 - mid, 0.f) +
               fmaxf(u2 - mid, 0.f) + fmaxf(u3 - mid, 0.f);
#pragma unroll
    for (int m = 1; m < 16; m <<= 1) sm += __shfl_xor(sm, m);
    const bool pos = (sm - 1.0f) > 0.0f;
    lo = pos ? mid : lo;
    hi = pos ? hi : mid;
  }
  const float tau = 0.5f * (lo + hi);
  const float p0 = fmaxf(u0 - tau, 0.f);
  const float p1 = fmaxf(u1 - tau, 0.f);
  const float p2 = fmaxf(u2 - tau, 0.f);
  const float p3 = fmaxf(u3 - tau, 0.f);
  float sum = p0 + p1 + p2 + p3;
#pragma unroll
  for (int m = 1; m < 16; m <<= 1) sum += __shfl_xor(sum, m);
  const float inv = 1.0f / (sum + 1e-8f);
  float4 pv;
  pv.x = p0 * inv; pv.y = p1 * inv; pv.z = p2 * inv; pv.w = p3 * inv;
  *(float4*)(out + (size_t)(brow + srow) * E_DIM + scol) = pv;
}

extern "C" void kernel_launch(void* const* d_in, const int* in_sizes, int n_in,
                              void* d_out, int out_size, void* d_ws, size_t ws_size,
                              hipStream_t stream) {
  const float* x  = (const float*)d_in[0];
  const float* w1 = (const float*)d_in[1];
  const float* b1 = (const float*)d_in[2];
  const float* w2 = (const float*)d_in[3];
  const float* b2 = (const float*)d_in[4];
  float* out = (float*)d_out;

  char* wsb = (char*)d_ws;
  f16* w1s = (f16*)wsb;                   // 2 MB
  f16* w2s = (f16*)(wsb + (2u << 20));    // 32 KB

  pack_kernel<<<520, 256, 0, stream>>>(w1, w1s, w2, w2s);
  fused_kernel<<<256, 512, 0, stream>>>(x, w1s, b1, w2s, b2, out);
}

// Round 10
// 56.782 us; speedup vs baseline: 1.2906x; 1.2906x over previous
//
#include <hip/hip_runtime.h>
#include <stdint.h>

typedef _Float16 f16;
typedef _Float16 f16x8 __attribute__((ext_vector_type(8)));
typedef _Float16 f16x4 __attribute__((ext_vector_type(4)));
typedef float f32x4 __attribute__((ext_vector_type(4)));

#define D_DIM 4096
#define H_DIM 256
#define E_DIM 64
#define BM 128
#define KSPLIT 4
#define NKT2 16                 // K-steps per slice: 1024/64
#define HP_SLICE (8192 * 256)   // f16 elems per hpart slice

// ---- merged pack: w1 [4096][256] -> w1s fragment order; w2 [256][64] -> w2s ----
// w1s f16 index: ((kt*16 + c16)*2 + kk)*512 + lane*8 + j
//   = w1[(kt*64 + kk*32 + (lane>>4)*8 + j)][c16*16 + (lane&15)]
__global__ void pack_kernel(const float* __restrict__ w1, f16* __restrict__ w1s,
                            const float* __restrict__ w2, f16* __restrict__ w2s) {
  const int b = blockIdx.x;
  const int t = threadIdx.x;
  if (b < 512) {
    const int u = b * 256 + t;
    const int lane = u & 63;
    const int kk = (u >> 6) & 1;
    const int c16 = (u >> 7) & 15;
    const int kt = u >> 11;
    const int g = lane >> 4, r = lane & 15;
    const int k0 = kt * 64 + kk * 32 + g * 8;
    const int col = c16 * 16 + r;
    f16x8 o;
#pragma unroll
    for (int j = 0; j < 8; ++j) o[j] = (f16)w1[(size_t)(k0 + j) * H_DIM + col];
    *(f16x8*)(w1s + (size_t)u * 8) = o;
  } else {
    const int u = (b - 512) * 256 + t;
    const int lane = u & 63;
    const int ks = (u >> 6) & 7;
    const int cg = u >> 9;
    const int g = lane >> 4, r = lane & 15;
    const int k0 = ks * 32 + g * 8;
    const int col = cg * 16 + r;
    f16x8 o;
#pragma unroll
    for (int j = 0; j < 8; ++j) o[j] = (f16)w2[(size_t)(k0 + j) * E_DIM + col];
    *(f16x8*)(w2s + (size_t)u * 8) = o;
  }
}

// ---- GEMM1 split-K, BM=128: A reg-staged->LDS (f16 swizzled, dbuf),
//      B DMA'd to LDS once per block-step via global_load_lds (issued == unique) ----
__launch_bounds__(512)
__global__ void gemm1_splitk_kernel(const float* __restrict__ x,
                                    const f16* __restrict__ w1s,
                                    f16* __restrict__ hpart) {
  __shared__ __align__(16) f16 Abuf[2][BM * 64];     // 2 x 16 KB
  __shared__ __align__(16) f16 Bbuf[2][16384];       // 2 x 32 KB (step tile, pack order)

  const int t = threadIdx.x;
  const int lane = t & 63;
  const int wn = t >> 6;
  const int wm = wn >> 2;       // 0..1  (64-row half)
  const int wc = wn & 3;        // 0..3  (64-col group)
  const int g = lane >> 4, r = lane & 15;
  const int bid = blockIdx.x;
  const int ks = bid & 3;
  const int brow = (bid >> 2) * BM;
  const int kph = (bid * 5) & 15;
#define KT(s) ((kph + (s)) & 15)

  // A staging: 4 float4/thread/step; i-th covers row i*32 + (t>>4)
  const float* xb = x + (size_t)(brow + (t >> 4)) * D_DIM + ks * 1024 + ((t & 15) << 2);
  const int stw_swz = (((t & 15) << 2) ^ (((t >> 4) & 7) << 3));
  const int stw_row0 = (t >> 4);

  // B step tile base in w1s (f16 elems): ks-slice + kt*16384
  const f16* bsl = w1s + (size_t)ks * (16 * 16384);

  f32x4 acc[4][4];
#pragma unroll
  for (int mf = 0; mf < 4; ++mf)
#pragma unroll
    for (int nf = 0; nf < 4; ++nf) acc[mf][nf] = (f32x4){0.f, 0.f, 0.f, 0.f};

  float4 xA[4];

#define LDX(kt)                                                         \
  {                                                                     \
    _Pragma("unroll") for (int i = 0; i < 4; ++i)                       \
      xA[i] = *(const float4*)(xb + (size_t)i * (32 * D_DIM) + (kt) * 64); \
  }
#define STW(p)                                                          \
  {                                                                     \
    _Pragma("unroll") for (int i = 0; i < 4; ++i) {                     \
      f16x4 hv_;                                                        \
      hv_[0] = (f16)xA[i].x; hv_[1] = (f16)xA[i].y;                     \
      hv_[2] = (f16)xA[i].z; hv_[3] = (f16)xA[i].w;                     \
      *(f16x4*)(&Abuf[p][(i * 32 + stw_row0) * 64 + stw_swz]) = hv_;    \
    }                                                                   \
  }
  // B DMA: 4 rounds x 512 threads x 16B = 32KB; LDS dest wave-uniform base,
  // global src per-lane (linear copy; pack order == fragment read order)
#define DMAB(p, kt)                                                     \
  {                                                                     \
    _Pragma("unroll") for (int q = 0; q < 4; ++q) {                     \
      const f16* gs_ = bsl + (size_t)(kt) * 16384 +                     \
                       (q * 512 + wn * 64 + lane) * 8;                  \
      __builtin_amdgcn_global_load_lds(                                 \
          (const __attribute__((address_space(1))) void*)gs_,           \
          (__attribute__((address_space(3))) void*)                     \
              (&Bbuf[p][(q * 512 + wn * 64) * 8]),                      \
          16, 0, 0);                                                    \
    }                                                                   \
  }
#define COMP(p)                                                                 \
  {                                                                             \
    _Pragma("unroll") for (int kk = 0; kk < 2; ++kk) {                          \
      const int kb_ = (kk * 32 + g * 8) ^ ((r & 7) << 3);                       \
      _Pragma("unroll") for (int mf = 0; mf < 4; ++mf) {                        \
        const int row_ = wm * 64 + mf * 16 + r;                                 \
        const f16x8 af_ = *(const f16x8*)(&Abuf[p][row_ * 64 + kb_]);           \
        _Pragma("unroll") for (int nf = 0; nf < 4; ++nf) {                      \
          const f16x8 bf_ =                                                     \
              *(const f16x8*)(&Bbuf[p][(wc * 8 + nf * 2 + kk) * 512 + lane * 8]); \
          acc[mf][nf] = __builtin_amdgcn_mfma_f32_16x16x32_f16(                 \
              af_, bf_, acc[mf][nf], 0, 0, 0);                                  \
        }                                                                       \
      }                                                                         \
    }                                                                           \
  }

  // prologue: B(0)->Bbuf[0]; x(0)->regs->Abuf[0]; x(1)->regs; sync
  DMAB(0, KT(0));
  LDX(KT(0));
  STW(0);
  LDX(KT(1));
  __syncthreads();

#pragma unroll 1
  for (int s = 0; s < NKT2; ++s) {
    const int p = s & 1;
    if (s + 1 < NKT2) {
      DMAB(p ^ 1, KT(s + 1));   // B(s+1) DMA, longest latency first
      STW(p ^ 1);               // A(s+1) from regs (compiler waits the x loads)
      if (s + 2 < NKT2) LDX(KT(s + 2));
    }
    COMP(p);
    __syncthreads();
  }

  // epilogue: store f16 partials hpart[ks][brow+row][col]
  f16* hp = hpart + (size_t)ks * HP_SLICE + (size_t)brow * H_DIM;
#pragma unroll
  for (int mf = 0; mf < 4; ++mf)
#pragma unroll
    for (int nf = 0; nf < 4; ++nf) {
      const int col = wc * 64 + nf * 16 + r;
#pragma unroll
      for (int j = 0; j < 4; ++j) {
        const int row = wm * 64 + mf * 16 + g * 4 + j;
        hp[(size_t)row * H_DIM + col] = (f16)acc[mf][nf][j];
      }
    }
}

// ---- reduce f16 partials + bias + relu + gemm2 + sparsemax (32 rows/block) ----
__launch_bounds__(512)
__global__ void reduce_fused_kernel(const f16* __restrict__ hpart,
                                    const float* __restrict__ b1,
                                    const f16* __restrict__ w2s,
                                    const float* __restrict__ b2,
                                    float* __restrict__ out) {
  __shared__ __align__(16) char smem[24576];
  f16* h_lds = (f16*)smem;                 // [32][256] f16, 8-granule XOR swizzle
  float* u_lds = (float*)(smem + 16384);   // [32][64]

  const int t = threadIdx.x;
  const int lane = t & 63;
  const int wn = t >> 6;
  const int g = lane >> 4, r = lane & 15;
  const int brow = blockIdx.x * 32;

  const int row = t >> 4;            // 0..31
  const int col0 = (t & 15) << 4;    // 0..240
  const f16* base = hpart + (size_t)(brow + row) * H_DIM + col0;
  float a[16];
#pragma unroll
  for (int j = 0; j < 16; ++j) a[j] = 0.f;
#pragma unroll
  for (int c = 0; c < KSPLIT; ++c) {
    const f16x8 va = *(const f16x8*)(base + (size_t)c * HP_SLICE);
    const f16x8 vb = *(const f16x8*)(base + (size_t)c * HP_SLICE + 8);
#pragma unroll
    for (int j = 0; j < 8; ++j) { a[j] += (float)va[j]; a[8 + j] += (float)vb[j]; }
  }
  {
    const int s8 = (row & 7) << 3;
    f16x8 h0, h1;
#pragma unroll
    for (int j = 0; j < 8; ++j) {
      h0[j] = (f16)fmaxf(a[j] + b1[col0 + j], 0.f);
      h1[j] = (f16)fmaxf(a[8 + j] + b1[col0 + 8 + j], 0.f);
    }
    *(f16x8*)(h_lds + row * 256 + (col0 ^ s8)) = h0;
    *(f16x8*)(h_lds + row * 256 + ((col0 + 8) ^ s8)) = h1;
  }
  __syncthreads();

  // gemm2: u = h @ w2 + b2 (one 16x16 tile per wave)
  const int rh2 = wn & 1;
  const int cg = wn >> 1;
  f32x4 acc2 = {0.f, 0.f, 0.f, 0.f};
  const f16* w2p = w2s + (size_t)(cg * 8) * 512 + lane * 8;
#pragma unroll
  for (int ksi = 0; ksi < 8; ++ksi) {
    const int arow = rh2 * 16 + r;
    const int kb = ksi * 32 + g * 8;
    const f16x8 af = *(const f16x8*)(h_lds + arow * 256 + (kb ^ ((arow & 7) << 3)));
    const f16x8 bf = *(const f16x8*)(w2p + ksi * 512);
    acc2 = __builtin_amdgcn_mfma_f32_16x16x32_f16(af, bf, acc2, 0, 0, 0);
  }
  {
    const int col = cg * 16 + r;
    const float bias = b2[col];
#pragma unroll
    for (int j = 0; j < 4; ++j) {
      const int rr = rh2 * 16 + g * 4 + j;
      u_lds[rr * 64 + col] = acc2[j] + bias;
    }
  }
  __syncthreads();

  // bisection sparsemax; 16 lanes/row, 4 vals/lane
  const int srow = wn * 4 + (lane >> 4);
  const int scol = (lane & 15) << 2;
  const float4 uv = *(const float4*)(u_lds + srow * 64 + scol);
  float u0 = uv.x, u1 = uv.y, u2 = uv.z, u3 = uv.w;

  float mx = fmaxf(fmaxf(u0, u1), fmaxf(u2, u3));
  float mn = fminf(fminf(u0, u1), fminf(u2, u3));
#pragma unroll
  for (int m = 1; m < 16; m <<= 1) {
    mx = fmaxf(mx, __shfl_xor(mx, m));
    mn = fminf(mn, __shfl_xor(mn, m));
  }
  float lo = mn - 10.0f, hi = mx;
#pragma unroll 1
  for (int it = 0; it < 32; ++it) {
    const float mid = 0.5f * (lo + hi);
    float sm = fmaxf(u0 - mid, 0.f) + fmaxf(u1 - mid, 0.f) +
               fmaxf(u2 - mid, 0.f) + fmaxf(u3 - mid, 0.f);
#pragma unroll
    for (int m = 1; m < 16; m <<= 1) sm += __shfl_xor(sm, m);
    const bool pos = (sm - 1.0f) > 0.0f;
    lo = pos ? mid : lo;
    hi = pos ? hi : mid;
  }
  const float tau = 0.5f * (lo + hi);
  const float p0 = fmaxf(u0 - tau, 0.f);
  const float p1 = fmaxf(u1 - tau, 0.f);
  const float p2 = fmaxf(u2 - tau, 0.f);
  const float p3 = fmaxf(u3 - tau, 0.f);
  float sum = p0 + p1 + p2 + p3;
#pragma unroll
  for (int m = 1; m < 16; m <<= 1) sum += __shfl_xor(sum, m);
  const float inv = 1.0f / (sum + 1e-8f);
  float4 pv;
  pv.x = p0 * inv; pv.y = p1 * inv; pv.z = p2 * inv; pv.w = p3 * inv;
  *(float4*)(out + (size_t)(brow + srow) * E_DIM + scol) = pv;
}

extern "C" void kernel_launch(void* const* d_in, const int* in_sizes, int n_in,
                              void* d_out, int out_size, void* d_ws, size_t ws_size,
                              hipStream_t stream) {
  const float* x  = (const float*)d_in[0];
  const float* w1 = (const float*)d_in[1];
  const float* b1 = (const float*)d_in[2];
  const float* w2 = (const float*)d_in[3];
  const float* b2 = (const float*)d_in[4];
  float* out = (float*)d_out;

  char* wsb = (char*)d_ws;
  f16* w1s = (f16*)wsb;                      // 2 MB
  f16* w2s = (f16*)(wsb + (2u << 20));       // 32 KB
  f16* hpart = (f16*)(wsb + (4u << 20));     // 4*8192*256 f16 = 16 MB

  pack_kernel<<<520, 256, 0, stream>>>(w1, w1s, w2, w2s);
  gemm1_splitk_kernel<<<256, 512, 0, stream>>>(x, w1s, hpart);
  reduce_fused_kernel<<<256, 512, 0, stream>>>(hpart, b1, w2s, b2, out);
}